// Round 7
// baseline (1478.657 us; speedup 1.0000x reference)
//
#include <hip/hip_runtime.h>
#include <math.h>

#define Nn     512
#define Ll     500
#define TSTEPS 800
#define NWG    32
#define NJ     16     // nodes per workgroup
#define NT     320    // 5 waves: wave0 control, waves 1-4 gather
#define NEEG   64
#define NB_    40
#define NH_    20
#define KBUF   8      // rotating exchange buffers (power of 2; skew<=2 needs >=5)
#define NE0CAP 2048   // global delay-0 edge cap (expected ~580)
#define SCALE_    524288.0f
#define INVSCALE_ (1.0f/524288.0f)

// d_ws layout (float/u32 indices)
#define OFF_SUMSQ  0
#define OFF_ABORT  1
#define OFF_NE0    2
#define OFF_CNT0   64                        // u32[512]
#define OFF_PFX    576                       // u32[513]
#define OFF_SLOT   1152                      // u32[512]
#define OFF_ROWSUM 1664                      // f32[512]
#define OFF_EEG    2176                      // f32[2560]
#define OFF_ZEND   4736                      // zero [0, OFF_ZEND)
#define OFF_ELIST  4736                      // u32[NE0CAP]
#define OFF_D0B    (OFF_ELIST + NE0CAP)      // u32[KBUF*NE0CAP]
#define OFF_TBUF   (OFF_D0B + KBUF*NE0CAP)   // u32[KBUF*Nn*NWG]
#define OFF_WS     (OFF_TBUF + KBUF*Nn*NWG)  // f32[512*512]
#define OFF_LMT    (OFF_WS + Nn*Nn)          // f32[64*512]

__device__ __forceinline__ float relu_(float x) { return fmaxf(x, 0.0f); }
__device__ __forceinline__ int sext25_(unsigned u) { return ((int)(u << 7)) >> 7; }

__global__ void k_ws(const float* __restrict__ wbb, const float* __restrict__ sc,
                     float* __restrict__ ws)
{
    int i = blockIdx.x, tid = threadIdx.x;
    float rs = 0.f, sq = 0.f;
    for (int j = tid; j < Nn; j += 256) {
        float wij = expf(wbb[i*Nn+j]) * sc[i*Nn+j];
        float wji = expf(wbb[j*Nn+i]) * sc[j*Nn+i];
        float v = log1pf(0.5f*(wij + wji));
        ws[OFF_WS + i*Nn + j] = v;
        rs += v; sq += v*v;
    }
    #pragma unroll
    for (int off = 32; off > 0; off >>= 1) { rs += __shfl_down(rs, off); sq += __shfl_down(sq, off); }
    __shared__ float srs[4], ssq[4];
    int wv = tid >> 6, ln = tid & 63;
    if (ln == 0) { srs[wv] = rs; ssq[wv] = sq; }
    __syncthreads();
    if (tid == 0) {
        ws[OFF_ROWSUM + i] = srs[0]+srs[1]+srs[2]+srs[3];
        atomicAdd(&ws[OFF_SUMSQ], ssq[0]+ssq[1]+ssq[2]+ssq[3]);
    }
}

__global__ void k_lmt(const float* __restrict__ lm, float* __restrict__ ws)
{
    int n = blockIdx.x*256 + threadIdx.x;
    if (n >= Nn) return;
    float s = 0.f;
    for (int e = 0; e < NEEG; ++e) s += lm[e*Nn + n];
    float mean = s * (1.0f/NEEG);
    for (int e = 0; e < NEEG; ++e) ws[OFF_LMT + e*Nn + n] = lm[e*Nn + n] - mean;
}

__global__ void k_prep1(const float* __restrict__ dist, const float* __restrict__ theta,
                        float* __restrict__ ws)
{
    int j = blockIdx.x;
    float den = 1.5f + relu_(theta[15]);
    unsigned* cnt0 = (unsigned*)ws + OFF_CNT0;
    for (int i = threadIdx.x; i < Nn; i += 256)
        if ((int)(dist[j*Nn+i] / den) == 0) atomicAdd(&cnt0[i], 1u);
}

__global__ void k_prep2(float* __restrict__ ws)
{
    if (threadIdx.x != 0) return;
    unsigned* cnt0 = (unsigned*)ws + OFF_CNT0;
    unsigned* pfx  = (unsigned*)ws + OFF_PFX;
    unsigned run = 0;
    for (int i = 0; i < Nn; ++i) { pfx[i] = run; run += cnt0[i]; }
    pfx[Nn] = run;
    ((unsigned*)ws)[OFF_NE0] = run;
}

__global__ void k_prep3(const float* __restrict__ dist, const float* __restrict__ theta,
                        float* __restrict__ ws)
{
    int j = blockIdx.x;
    float den = 1.5f + relu_(theta[15]);
    unsigned* pfx  = (unsigned*)ws + OFF_PFX;
    unsigned* slot = (unsigned*)ws + OFF_SLOT;
    unsigned* el   = (unsigned*)ws + OFF_ELIST;
    for (int i = threadIdx.x; i < Nn; i += 256) {
        if ((int)(dist[j*Nn+i] / den) == 0) {
            unsigned pos = pfx[i] + atomicAdd(&slot[i], 1u);
            if (pos < NE0CAP) el[pos] = ((unsigned)i << 16) | (unsigned)j;
        }
    }
}

__global__ __launch_bounds__(NT) void k_main(
    const float* __restrict__ input, const float* __restrict__ noise_in,
    const float* __restrict__ hx, const float* __restrict__ hE,
    const float* __restrict__ dist, const float* __restrict__ W_in,
    const float* __restrict__ theta, float* __restrict__ ws)
{
    __shared__ float hist[NJ][512];          // 32 KB
    __shared__ float wn[NJ][Nn];             // 32 KB (d0 edges zeroed)
    __shared__ unsigned short dd[NJ][Nn];    // 16 KB
    __shared__ float u_l[TSTEPS*2];          // 6.4 KB
    __shared__ float lmt_l[NEEG][NJ];        // 4 KB
    __shared__ float eeg_l[NB_][NEEG];       // 10.2 KB
    __shared__ unsigned elist_l[NE0CAP];     // 8 KB
    __shared__ float eim[NJ];
    __shared__ float d0acc[NJ];
    __shared__ int   caps_s[2];
    __shared__ unsigned abort_s;

    const int w   = blockIdx.x;
    const int tid = threadIdx.x;
    const int j0  = w*NJ;
    float* histf  = &hist[0][0];

    float th[16];
    #pragma unroll
    for (int k = 0; k < 16; ++k) th[k] = theta[k];
    const float kg   = 0.01f + relu_(th[0]);
    const float kc1  = 0.01f + relu_(th[1]);
    const float kc2  = 0.01f + relu_(th[2]);
    const float kc3  = 0.01f + relu_(th[3]);
    const float kc4  = 0.01f + relu_(th[4]);
    const float kstd = 150.0f + relu_(th[5]);
    const float rA   = relu_(th[6]);
    const float aa   = 1.0f + relu_(th[7]);
    const float rB   = relu_(th[8]);
    const float ab   = 1.0f + relu_(th[9]);
    const float vmax = th[10], v0p = th[11], rr = th[12];
    const float den  = 1.5f + relu_(th[15]);
    const float invnorm = 1.0f / sqrtf(ws[OFF_SUMSQ]);

    if (tid == 0) abort_s = 0u;

    for (int idx = tid; idx < NJ*Nn; idx += NT) {
        int jl = idx >> 9, i = idx & 511;
        int jg = j0 + jl;
        wn[jl][i] = ws[OFF_WS + jg*Nn + i] * invnorm;
        dd[jl][i] = (unsigned short)(int)(dist[jg*Nn + i] / den);
    }
    for (int idx = tid; idx < NJ*512; idx += NT) {
        int jl = idx >> 9, s = idx & 511;
        int k = 511 - s;
        hist[jl][s] = (k < Ll) ? hE[(j0+jl)*Ll + k] : 0.0f;
    }
    for (int idx = tid; idx < TSTEPS*2; idx += NT) {
        int t = idx >> 1, s = idx & 1;
        int tt = (t % NH_)*NB_ + (t / NH_);
        u_l[idx] = input[tt*2 + s];
    }
    for (int idx = tid; idx < NEEG*NJ; idx += NT) {
        int e = idx / NJ, jl = idx - e*NJ;
        lmt_l[e][jl] = ws[OFF_LMT + e*Nn + j0 + jl];
    }
    float stM=0,stE=0,stI=0,stMv=0,stEv=0,stIv=0, dgd_r=0, win0=0, win1=0;
    const float* nz_base = nullptr;
    if (tid < NJ) {
        stM  = hx[(j0+tid)*6+0]; stE  = hx[(j0+tid)*6+1]; stI  = hx[(j0+tid)*6+2];
        stMv = hx[(j0+tid)*6+3]; stEv = hx[(j0+tid)*6+4]; stIv = hx[(j0+tid)*6+5];
        dgd_r = -ws[OFF_ROWSUM + j0 + tid] * invnorm;
        win0 = W_in[(j0+tid)*2+0]; win1 = W_in[(j0+tid)*2+1];
        nz_base = noise_in + (size_t)(j0+tid)*(NH_*NB_*3);
    }
    __syncthreads();

    const unsigned ne0 = ((const unsigned*)ws)[OFF_NE0];
    unsigned* abortf = (unsigned*)ws + OFF_ABORT;
    unsigned* d0b    = (unsigned*)ws + OFF_D0B;
    unsigned* tbuf   = (unsigned*)ws + OFF_TBUF;
    if (ne0 > NE0CAP) { if (tid == 0) *abortf = 1u; return; }

    for (int idx = tid; idx < (int)ne0; idx += NT)
        elist_l[idx] = ((const unsigned*)ws)[OFF_ELIST + idx];
    __syncthreads();

    // wave0: producer edges (source j in own range) and consumer edges (target in own range)
    int  p_pos = 0, p_jl = 0; float p_w = 0.f; bool has_p = false;
    int  c_off = 0, c_iloc = 0; bool has_c = false;
    const unsigned* pfxg = (const unsigned*)ws + OFF_PFX;
    const int pA = (int)pfxg[j0], pB = (int)pfxg[j0 + NJ];
    const int ncd0 = pB - pA;
    if (tid < 64) {
        int c = 0;
        for (int e = 0; e < (int)ne0; ++e) {
            unsigned u = elist_l[e];
            int jr = (int)(u & 0xFFFFu) - j0;
            if ((unsigned)jr < (unsigned)NJ) {
                if (c == tid) { p_pos = e; p_jl = jr; p_w = wn[jr][u >> 16]; has_p = true; }
                ++c;
            }
        }
        if (tid == 0) { caps_s[0] = c; caps_s[1] = ncd0; }
        if (tid < ncd0) {
            unsigned u = elist_l[pA + tid];
            has_c = true; c_off = pA + tid; c_iloc = (int)(u >> 16) - j0;
        }
    }
    __syncthreads();
    if (caps_s[0] > 64 || caps_s[1] > 64) { if (tid == 0) *abortf = 1u; return; }
    // mask d0 edges out of bulk weights
    for (int e = tid; e < (int)ne0; e += NT) {
        unsigned u = elist_l[e];
        int jr = (int)(u & 0xFFFFu) - j0;
        if ((unsigned)jr < (unsigned)NJ) wn[jr][u >> 16] = 0.f;
    }
    __syncthreads();

    // gather register preload + prologue: bulk(0)->buf0 tag0, bulk(1)->buf1 tag1, d0(0)->ring0
    float wnr0[NJ], wnr1[NJ];
    int   of0[NJ],  of1[NJ];
    if (tid >= 64) {
        const int gt = tid - 64;
        float pa0=0.f, pa1=0.f, pb0=0.f, pb1=0.f;
        #pragma unroll
        for (int jl = 0; jl < NJ; ++jl) {
            int da = (int)dd[jl][gt], db = (int)dd[jl][gt+256];
            wnr0[jl] = wn[jl][gt];  wnr1[jl] = wn[jl][gt+256];
            of0[jl] = (1 - da) & 511;  of1[jl] = (1 - db) & 511;
            pa0 += wnr0[jl] * hist[jl][(511 - da) & 511];
            pa1 += wnr1[jl] * hist[jl][(511 - db) & 511];
            pb0 += wnr0[jl] * hist[jl][(512 - da) & 511];
            pb1 += wnr1[jl] * hist[jl][(512 - db) & 511];
        }
        const int i0 = gt, i1 = gt + 256;
        const int w0 = ((i0>>4)<<9) + ((i0&15)<<5) + w;
        const int w1 = ((i1>>4)<<9) + ((i1&15)<<5) + w;
        __hip_atomic_store(&tbuf[w0], (unsigned)(int)lrintf(pa0*SCALE_) & 0x1FFFFFFu, __ATOMIC_RELAXED, __HIP_MEMORY_SCOPE_AGENT);
        __hip_atomic_store(&tbuf[w1], (unsigned)(int)lrintf(pa1*SCALE_) & 0x1FFFFFFu, __ATOMIC_RELAXED, __HIP_MEMORY_SCOPE_AGENT);
        __hip_atomic_store(&tbuf[Nn*NWG + w0], (1u<<25) | ((unsigned)(int)lrintf(pb0*SCALE_) & 0x1FFFFFFu), __ATOMIC_RELAXED, __HIP_MEMORY_SCOPE_AGENT);
        __hip_atomic_store(&tbuf[Nn*NWG + w1], (1u<<25) | ((unsigned)(int)lrintf(pb1*SCALE_) & 0x1FFFFFFu), __ATOMIC_RELAXED, __HIP_MEMORY_SCOPE_AGENT);
    } else if (has_p) {
        __hip_atomic_store(&d0b[p_pos], (unsigned)(int)lrintf(p_w*hist[p_jl][511]*SCALE_) & 0x1FFFFFFu,
                           __ATOMIC_RELAXED, __HIP_MEMORY_SCOPE_AGENT);
    }

    int thc = 0, tbc = 0;               // t%20, t/20
    for (int t = 0; t < TSTEPS; ++t) {
        // ================= pre-barrier phase =================
        float nM_pre=0.f, nE_pre=0.f, nI_pre=0.f;
        float nz=0.f, stim=0.f, rE0=0.f, nMv=0.f, nIv=0.f;
        unsigned long long a0=0, a1=0, a2=0, a3=0;
        unsigned cw = 0;
        if (tid < 64) {
            // --- pre-issue ALL loads FIRST: in-order vmcnt retire means their use
            //     never waits on the d0 store issued below ---
            const unsigned long long* pl =
                (const unsigned long long*)(tbuf + (t & (KBUF-1))*(Nn*NWG) + w*512) + (size_t)tid*4;
            a0 = __hip_atomic_load(pl+0, __ATOMIC_RELAXED, __HIP_MEMORY_SCOPE_AGENT);
            a1 = __hip_atomic_load(pl+1, __ATOMIC_RELAXED, __HIP_MEMORY_SCOPE_AGENT);
            a2 = __hip_atomic_load(pl+2, __ATOMIC_RELAXED, __HIP_MEMORY_SCOPE_AGENT);
            a3 = __hip_atomic_load(pl+3, __ATOMIC_RELAXED, __HIP_MEMORY_SCOPE_AGENT);
            if (has_c) cw = __hip_atomic_load(&d0b[(t & (KBUF-1))*NE0CAP + c_off], __ATOMIC_RELAXED, __HIP_MEMORY_SCOPE_AGENT);
            if (tid < NJ) nz = nz_base[(thc*NB_ + tbc)*3];

            if (tid < NJ) {
                nM_pre = stM + 0.05f*stMv;
                nE_pre = stE + 0.05f*stEv;
                nI_pre = stI + 0.05f*stIv;
            }
            // d0 publish for t+1 (flight overlaps the rest of this iteration)
            float esrc = __shfl(nE_pre, p_jl);
            if (has_p && t < TSTEPS-1) {
                unsigned v = ((unsigned)((t+1) & 127) << 25) |
                             ((unsigned)(int)lrintf(p_w*esrc*SCALE_) & 0x1FFFFFFu);
                __hip_atomic_store(&d0b[((t+1) & (KBUF-1))*NE0CAP + p_pos], v, __ATOMIC_RELAXED, __HIP_MEMORY_SCOPE_AGENT);
            }
            if (tid < NJ) {
                hist[tid][t & 511] = nE_pre;
                d0acc[tid] = 0.f;
                if (thc == NH_-1) eim[tid] = nE_pre - nI_pre;
            }
            if (tid < NJ) {
                stim = win0*u_l[2*t] + win1*u_l[2*t+1];
                float rM  = vmax / (1.0f + expf(-rr*((stE - stI) - v0p)));
                float s1v = vmax / (1.0f + expf(-rr*((kc1*stM)  - v0p)));
                float s3v = vmax / (1.0f + expf(-rr*((kc3*stM)  - v0p)));
                float rI  = kc4*s3v;
                rE0 = kg*(dgd_r*stE) + kc2*s1v;
                nMv = stMv + 0.05f*(rA*aa*(500.0f*tanhf(rM*0.002f)) - 2.0f*aa*stMv - aa*aa*stM);
                nIv = stIv + 0.05f*(rB*ab*(500.0f*tanhf(rI*0.002f)) - 2.0f*ab*stIv - ab*ab*stI);
            }
        }
        asm volatile("s_waitcnt lgkmcnt(0)" ::: "memory");   // drain LDS writes only
        __builtin_amdgcn_s_barrier();                        // vm ops stay in flight
        __builtin_amdgcn_sched_barrier(0);
        if (abort_s) break;

        // ================= post-barrier phase =================
        if (tid < 64) {
            const unsigned tg = (unsigned)(t & 127);
            bool okb = (((unsigned)(a0>>25)&127u)==tg) && ((unsigned)(a0>>57)==tg)
                    && (((unsigned)(a1>>25)&127u)==tg) && ((unsigned)(a1>>57)==tg)
                    && (((unsigned)(a2>>25)&127u)==tg) && ((unsigned)(a2>>57)==tg)
                    && (((unsigned)(a3>>25)&127u)==tg) && ((unsigned)(a3>>57)==tg);
            bool okc = !has_c || ((cw >> 25) == tg);
            unsigned spins = 0; bool to = false;
            const unsigned long long* pl =
                (const unsigned long long*)(tbuf + (t & (KBUF-1))*(Nn*NWG) + w*512) + (size_t)tid*4;
            while (!__all(okb && okc)) {
                if (!okb) {
                    a0 = __hip_atomic_load(pl+0, __ATOMIC_RELAXED, __HIP_MEMORY_SCOPE_AGENT);
                    a1 = __hip_atomic_load(pl+1, __ATOMIC_RELAXED, __HIP_MEMORY_SCOPE_AGENT);
                    a2 = __hip_atomic_load(pl+2, __ATOMIC_RELAXED, __HIP_MEMORY_SCOPE_AGENT);
                    a3 = __hip_atomic_load(pl+3, __ATOMIC_RELAXED, __HIP_MEMORY_SCOPE_AGENT);
                    okb = (((unsigned)(a0>>25)&127u)==tg) && ((unsigned)(a0>>57)==tg)
                       && (((unsigned)(a1>>25)&127u)==tg) && ((unsigned)(a1>>57)==tg)
                       && (((unsigned)(a2>>25)&127u)==tg) && ((unsigned)(a2>>57)==tg)
                       && (((unsigned)(a3>>25)&127u)==tg) && ((unsigned)(a3>>57)==tg);
                }
                if (!okc) {
                    cw = __hip_atomic_load(&d0b[(t & (KBUF-1))*NE0CAP + c_off], __ATOMIC_RELAXED, __HIP_MEMORY_SCOPE_AGENT);
                    okc = ((cw >> 25) == tg);
                }
                if ((++spins & 255u) == 0u) {
                    if (__hip_atomic_load(abortf, __ATOMIC_RELAXED, __HIP_MEMORY_SCOPE_AGENT) != 0u ||
                        spins > (1u<<20)) {
                        __hip_atomic_store(abortf, 1u, __ATOMIC_RELAXED, __HIP_MEMORY_SCOPE_AGENT);
                        to = true; break;
                    }
                }
            }
            if (to) {
                if (tid == 0) abort_s = 1u;
            } else {
                int qs = sext25_((unsigned)a0) + sext25_((unsigned)(a0>>32))
                       + sext25_((unsigned)a1) + sext25_((unsigned)(a1>>32))
                       + sext25_((unsigned)a2) + sext25_((unsigned)(a2>>32))
                       + sext25_((unsigned)a3) + sext25_((unsigned)(a3>>32));
                qs += __shfl_xor(qs, 1);
                qs += __shfl_xor(qs, 2);
                if (has_c) atomicAdd(&d0acc[c_iloc], (float)sext25_(cw) * INVSCALE_);
                asm volatile("s_waitcnt lgkmcnt(0)" ::: "memory");
                int qtot = __shfl(qs, (tid & 15)*4);
                if (tid < NJ) {
                    float LEd = (float)qtot * INVSCALE_ + d0acc[tid];
                    float rE = rE0 + kstd*nz + kg*LEd;
                    float nEv = stEv + 0.05f*(rA*aa*(stim + 500.0f*tanhf(rE*0.002f)) - 2.0f*aa*stEv - aa*aa*stE);
                    stM = nM_pre; stE = nE_pre; stI = nI_pre;
                    stMv = nMv; stEv = nEv; stIv = nIv;
                }
            }
        } else {
            // gather waves: bulk(t+2), published two steps ahead of consumption
            if (t <= TSTEPS-3) {
                const int gt = tid - 64;
                float g0 = 0.f, g1 = 0.f;
                #pragma unroll
                for (int jl = 0; jl < NJ; ++jl) {
                    g0 += wnr0[jl] * histf[jl*512 + of0[jl]];
                    g1 += wnr1[jl] * histf[jl*512 + of1[jl]];
                    of0[jl] = (of0[jl] + 1) & 511;
                    of1[jl] = (of1[jl] + 1) & 511;
                }
                const unsigned tg2 = (unsigned)((t+2) & 127) << 25;
                unsigned* bufn = tbuf + ((t+2) & (KBUF-1))*(Nn*NWG);
                const int i0 = gt, i1 = gt + 256;
                __hip_atomic_store(&bufn[((i0>>4)<<9) + ((i0&15)<<5) + w],
                                   tg2 | ((unsigned)(int)lrintf(g0*SCALE_) & 0x1FFFFFFu),
                                   __ATOMIC_RELAXED, __HIP_MEMORY_SCOPE_AGENT);
                __hip_atomic_store(&bufn[((i1>>4)<<9) + ((i1&15)<<5) + w],
                                   tg2 | ((unsigned)(int)lrintf(g1*SCALE_) & 0x1FFFFFFu),
                                   __ATOMIC_RELAXED, __HIP_MEMORY_SCOPE_AGENT);
            }
            if (thc == NH_-1 && tid < 64 + NEEG) {
                int e = tid - 64;
                float s = 0.f;
                #pragma unroll
                for (int jl = 0; jl < NJ; ++jl) s += lmt_l[e][jl]*eim[jl];
                eeg_l[tbc][e] = s;
            }
        }
        if (thc == NH_-1) { thc = 0; ++tbc; } else ++thc;
    }

    __syncthreads();
    if (abort_s == 0u) {
        const float* el = &eeg_l[0][0];
        for (int idx = tid; idx < NB_*NEEG; idx += NT)
            atomicAdd(&ws[OFF_EEG + idx], el[idx]);
    }
}

__global__ void k_out(const float* __restrict__ ws, const float* __restrict__ theta,
                      float* __restrict__ out)
{
    int idx = blockIdx.x*256 + threadIdx.x;
    if (idx < NB_*NEEG) out[idx] = 0.01f*theta[13]*ws[OFF_EEG + idx] - theta[14];
}

extern "C" void kernel_launch(void* const* d_in, const int* in_sizes, int n_in,
                              void* d_out, int out_size, void* d_ws, size_t ws_size,
                              hipStream_t stream)
{
    const float* input    = (const float*)d_in[0];
    const float* noise_in = (const float*)d_in[1];
    const float* hx       = (const float*)d_in[3];
    const float* hE       = (const float*)d_in[4];
    const float* sc       = (const float*)d_in[5];
    const float* dist     = (const float*)d_in[6];
    const float* w_bb     = (const float*)d_in[7];
    const float* W_in     = (const float*)d_in[8];
    const float* lm       = (const float*)d_in[10];
    const float* theta    = (const float*)d_in[11];
    float* ws  = (float*)d_ws;
    float* out = (float*)d_out;

    hipMemsetAsync(d_ws, 0, (size_t)OFF_ZEND*4, stream);
    hipMemsetAsync((char*)d_ws + (size_t)OFF_ELIST*4, 0xFF,
                   (size_t)(OFF_TBUF + KBUF*Nn*NWG - OFF_ELIST)*4, stream);   // tags=127
    k_ws   <<<Nn, 256, 0, stream>>>(w_bb, sc, ws);
    k_lmt  <<<(Nn + 255)/256, 256, 0, stream>>>(lm, ws);
    k_prep1<<<Nn, 256, 0, stream>>>(dist, theta, ws);
    k_prep2<<<1, 64, 0, stream>>>(ws);
    k_prep3<<<Nn, 256, 0, stream>>>(dist, theta, ws);
    k_main <<<NWG, NT, 0, stream>>>(input, noise_in, hx, hE, dist, W_in, theta, ws);
    k_out  <<<(NB_*NEEG + 255)/256, 256, 0, stream>>>(ws, theta, out);
}

// Round 8
// 874.782 us; speedup vs baseline: 1.6903x; 1.6903x over previous
//
#include <hip/hip_runtime.h>
#include <math.h>

#define Nn     512
#define Ll     500
#define TSTEPS 800
#define NWG    32
#define NJ     16     // nodes per workgroup
#define NT     576    // 9 waves: wave0 control, waves 1-8 gather (one target per lane)
#define NEEG   64
#define NB_    40
#define NH_    20
#define SCALE_    524288.0f        // 2^19 fixed point
#define INVSCALE_ (1.0f/524288.0f)

// d_ws layout in floats
#define OFF_SUMSQ  0
#define OFF_ABORT  1                      // u32
#define OFF_ROWSUM 64                     // 512 f32
#define OFF_EEG    576                    // 2560 f32
#define OFF_ZEND   3200                   // zero [0, OFF_ZEND)
#define OFF_TBUF   3200                   // u32[3 * 32 * 512] producer-major tagged exchange
#define TBUF_WORDS (3*Nn*NWG)             // 49152
#define OFF_WS     (OFF_TBUF + TBUF_WORDS)    // 52352
#define OFF_LMT    (OFF_WS + Nn*Nn)           // + 64*512

__device__ __forceinline__ float relu_(float x) { return fmaxf(x, 0.0f); }
__device__ __forceinline__ int sext25_(unsigned u) { return ((int)(u << 7)) >> 7; }

__global__ void k_ws(const float* __restrict__ wbb, const float* __restrict__ sc,
                     float* __restrict__ ws)
{
    int i = blockIdx.x, tid = threadIdx.x;
    float rs = 0.f, sq = 0.f;
    for (int j = tid; j < Nn; j += 256) {
        float wij = expf(wbb[i*Nn+j]) * sc[i*Nn+j];
        float wji = expf(wbb[j*Nn+i]) * sc[j*Nn+i];
        float v = log1pf(0.5f*(wij + wji));
        ws[OFF_WS + i*Nn + j] = v;
        rs += v; sq += v*v;
    }
    #pragma unroll
    for (int off = 32; off > 0; off >>= 1) { rs += __shfl_down(rs, off); sq += __shfl_down(sq, off); }
    __shared__ float srs[4], ssq[4];
    int wv = tid >> 6, ln = tid & 63;
    if (ln == 0) { srs[wv] = rs; ssq[wv] = sq; }
    __syncthreads();
    if (tid == 0) {
        ws[OFF_ROWSUM + i] = srs[0]+srs[1]+srs[2]+srs[3];
        atomicAdd(&ws[OFF_SUMSQ], ssq[0]+ssq[1]+ssq[2]+ssq[3]);
    }
}

__global__ void k_lmt(const float* __restrict__ lm, float* __restrict__ ws)
{
    int n = blockIdx.x*256 + threadIdx.x;
    if (n >= Nn) return;
    float s = 0.f;
    for (int e = 0; e < NEEG; ++e) s += lm[e*Nn + n];
    float mean = s * (1.0f/NEEG);
    for (int e = 0; e < NEEG; ++e) ws[OFF_LMT + e*Nn + n] = lm[e*Nn + n] - mean;
}

__global__ __launch_bounds__(NT) void k_main(
    const float* __restrict__ input, const float* __restrict__ noise_in,
    const float* __restrict__ hx, const float* __restrict__ hE,
    const float* __restrict__ dist, const float* __restrict__ W_in,
    const float* __restrict__ theta, float* __restrict__ ws)
{
    __shared__ float hist[NJ][512];          // 32 KB circular E-history
    __shared__ float wn[NJ][Nn];             // 32 KB weights (full, incl. delay-0)
    __shared__ unsigned short dd[NJ][Nn];    // 16 KB delays
    __shared__ float u_l[TSTEPS*2];          // 6.4 KB stimulus
    __shared__ float lmt_l[NEEG][NJ];        // 4 KB
    __shared__ float eeg_l[NB_][NEEG];       // 10.2 KB
    __shared__ float eim[NJ];
    __shared__ unsigned abort_s;

    const int w   = blockIdx.x;
    const int tid = threadIdx.x;
    const int j0  = w*NJ;
    float* histf  = &hist[0][0];

    float th[16];
    #pragma unroll
    for (int k = 0; k < 16; ++k) th[k] = theta[k];
    const float kg   = 0.01f + relu_(th[0]);
    const float kc1  = 0.01f + relu_(th[1]);
    const float kc2  = 0.01f + relu_(th[2]);
    const float kc3  = 0.01f + relu_(th[3]);
    const float kc4  = 0.01f + relu_(th[4]);
    const float kstd = 150.0f + relu_(th[5]);
    const float rA   = relu_(th[6]);
    const float aa   = 1.0f + relu_(th[7]);
    const float rB   = relu_(th[8]);
    const float ab   = 1.0f + relu_(th[9]);
    const float vmax = th[10], v0p = th[11], rr = th[12];
    const float den  = 1.5f + relu_(th[15]);
    const float invnorm = 1.0f / sqrtf(ws[OFF_SUMSQ]);

    if (tid == 0) abort_s = 0u;

    for (int idx = tid; idx < NJ*Nn; idx += NT) {
        int jl = idx >> 9, i = idx & 511;
        int jg = j0 + jl;
        wn[jl][i] = ws[OFF_WS + jg*Nn + i] * invnorm;
        dd[jl][i] = (unsigned short)(int)(dist[jg*Nn + i] / den);
    }
    // slot s holds E(tau), s = tau mod 512; initial: tau=-1-k -> hE[:,k]
    for (int idx = tid; idx < NJ*512; idx += NT) {
        int jl = idx >> 9, s = idx & 511;
        int k = 511 - s;
        hist[jl][s] = (k < Ll) ? hE[(j0+jl)*Ll + k] : 0.0f;
    }
    for (int idx = tid; idx < TSTEPS*2; idx += NT) {
        int t = idx >> 1, s = idx & 1;
        int tt = (t % NH_)*NB_ + (t / NH_);
        u_l[idx] = input[tt*2 + s];
    }
    for (int idx = tid; idx < NEEG*NJ; idx += NT) {
        int e = idx / NJ, jl = idx - e*NJ;
        lmt_l[e][jl] = ws[OFF_LMT + e*Nn + j0 + jl];
    }
    // wave0 per-lane ODE state + params
    float stM=0,stE=0,stI=0,stMv=0,stEv=0,stIv=0, dgd_r=0, win0=0, win1=0;
    const float* nz_base = nullptr;
    if (tid < NJ) {
        stM  = hx[(j0+tid)*6+0]; stE  = hx[(j0+tid)*6+1]; stI  = hx[(j0+tid)*6+2];
        stMv = hx[(j0+tid)*6+3]; stEv = hx[(j0+tid)*6+4]; stIv = hx[(j0+tid)*6+5];
        dgd_r = -ws[OFF_ROWSUM + j0 + tid] * invnorm;
        win0 = W_in[(j0+tid)*2+0]; win1 = W_in[(j0+tid)*2+1];
        nz_base = noise_in + (size_t)(j0+tid)*(NH_*NB_*3);
    }
    __syncthreads();

    unsigned* tbuf   = (unsigned*)ws + OFF_TBUF;
    unsigned* abortf = (unsigned*)ws + OFF_ABORT;

    // gather-lane register preload + prologue publish (partials(0) -> buf0, tag0)
    // producer-major: word = buf*16384 + w*512 + target  (coalesced stores)
    float wnr[NJ];
    int   ofs[NJ];
    if (tid >= 64) {
        const int gt = tid - 64;
        float p = 0.f;
        #pragma unroll
        for (int jl = 0; jl < NJ; ++jl) {
            int d = (int)dd[jl][gt];
            wnr[jl] = wn[jl][gt];
            ofs[jl] = (0 - d) & 511;
            p += wnr[jl] * hist[jl][(511 - d) & 511];
        }
        __hip_atomic_store(&tbuf[w*512 + gt],
                           (unsigned)(int)lrintf(p*SCALE_) & 0x1FFFFFFu,
                           __ATOMIC_RELAXED, __HIP_MEMORY_SCOPE_AGENT);
    }

    int thc = 0, tbc = 0;               // t%20, t/20
    for (int t = 0; t < TSTEPS; ++t) {
        // ---- pre-phase (tiny): positions are coupling-independent ----
        float nM_pre=0.f, nE_pre=0.f, nI_pre=0.f;
        if (tid < NJ) {
            nM_pre = stM + 0.05f*stMv;
            nE_pre = stE + 0.05f*stEv;
            nI_pre = stI + 0.05f*stIv;
            hist[tid][t & 511] = nE_pre;
            if (thc == NH_-1) eim[tid] = nE_pre - nI_pre;
        }
        __syncthreads();                              // B1: hist[t] visible

        if (tid >= 64) {
            // ---- gather lanes: full partials (incl. d0) for step t+1 ----
            const int gt = tid - 64;
            float g = 0.f;
            #pragma unroll
            for (int jl = 0; jl < NJ; ++jl) {
                g += wnr[jl] * histf[jl*512 + ofs[jl]];
                ofs[jl] = (ofs[jl] + 1) & 511;
            }
            if (t < TSTEPS-1) {
                unsigned* bufn = tbuf + ((t+1) % 3)*(Nn*NWG);
                __hip_atomic_store(&bufn[w*512 + gt],
                                   ((unsigned)((t+1) & 127) << 25) |
                                   ((unsigned)(int)lrintf(g*SCALE_) & 0x1FFFFFFu),
                                   __ATOMIC_RELAXED, __HIP_MEMORY_SCOPE_AGENT);
            }
            // wave 1: EEG dot at inner-scan boundary (reads eim written pre-B1)
            if (thc == NH_-1 && tid < 64 + NEEG) {
                int e = tid - 64;
                float s = 0.f;
                #pragma unroll
                for (int jl = 0; jl < NJ; ++jl) s += lmt_l[e][jl]*eim[jl];
                eeg_l[tbc][e] = s;
            }
        } else {
            // ---- control wave: poll 512 words (8/lane), reduce, ODE ----
            const int il = tid & 15;
            const int pbase = (tid >> 4) * 8;     // producer group: 0,8,16,24
            const unsigned* pb = tbuf + (t % 3)*(Nn*NWG) + j0 + il;
            unsigned v0,v1,v2,v3,v4,v5,v6,v7;
            v0 = __hip_atomic_load(&pb[(pbase+0)*512], __ATOMIC_RELAXED, __HIP_MEMORY_SCOPE_AGENT);
            v1 = __hip_atomic_load(&pb[(pbase+1)*512], __ATOMIC_RELAXED, __HIP_MEMORY_SCOPE_AGENT);
            v2 = __hip_atomic_load(&pb[(pbase+2)*512], __ATOMIC_RELAXED, __HIP_MEMORY_SCOPE_AGENT);
            v3 = __hip_atomic_load(&pb[(pbase+3)*512], __ATOMIC_RELAXED, __HIP_MEMORY_SCOPE_AGENT);
            v4 = __hip_atomic_load(&pb[(pbase+4)*512], __ATOMIC_RELAXED, __HIP_MEMORY_SCOPE_AGENT);
            v5 = __hip_atomic_load(&pb[(pbase+5)*512], __ATOMIC_RELAXED, __HIP_MEMORY_SCOPE_AGENT);
            v6 = __hip_atomic_load(&pb[(pbase+6)*512], __ATOMIC_RELAXED, __HIP_MEMORY_SCOPE_AGENT);
            v7 = __hip_atomic_load(&pb[(pbase+7)*512], __ATOMIC_RELAXED, __HIP_MEMORY_SCOPE_AGENT);

            // coupling-independent ODE precompute runs under the load shadow
            float nz=0.f, stim=0.f, rE0=0.f, nMv=0.f, nIv=0.f;
            if (tid < NJ) {
                nz = nz_base[(thc*NB_ + tbc)*3];
                stim = win0*u_l[2*t] + win1*u_l[2*t+1];
                float rM  = vmax / (1.0f + expf(-rr*((stE - stI) - v0p)));
                float s1v = vmax / (1.0f + expf(-rr*((kc1*stM)  - v0p)));
                float s3v = vmax / (1.0f + expf(-rr*((kc3*stM)  - v0p)));
                float rI  = kc4*s3v;
                rE0 = kg*(dgd_r*stE) + kc2*s1v;
                nMv = stMv + 0.05f*(rA*aa*(500.0f*tanhf(rM*0.002f)) - 2.0f*aa*stMv - aa*aa*stM);
                nIv = stIv + 0.05f*(rB*ab*(500.0f*tanhf(rI*0.002f)) - 2.0f*ab*stIv - ab*ab*stI);
            }

            const unsigned tg = (unsigned)(t & 127);
            bool ok = ((v0>>25)==tg) && ((v1>>25)==tg) && ((v2>>25)==tg) && ((v3>>25)==tg)
                   && ((v4>>25)==tg) && ((v5>>25)==tg) && ((v6>>25)==tg) && ((v7>>25)==tg);
            unsigned spins = 0; bool to = false;
            while (!__all(ok)) {
                if (!ok) {
                    v0 = __hip_atomic_load(&pb[(pbase+0)*512], __ATOMIC_RELAXED, __HIP_MEMORY_SCOPE_AGENT);
                    v1 = __hip_atomic_load(&pb[(pbase+1)*512], __ATOMIC_RELAXED, __HIP_MEMORY_SCOPE_AGENT);
                    v2 = __hip_atomic_load(&pb[(pbase+2)*512], __ATOMIC_RELAXED, __HIP_MEMORY_SCOPE_AGENT);
                    v3 = __hip_atomic_load(&pb[(pbase+3)*512], __ATOMIC_RELAXED, __HIP_MEMORY_SCOPE_AGENT);
                    v4 = __hip_atomic_load(&pb[(pbase+4)*512], __ATOMIC_RELAXED, __HIP_MEMORY_SCOPE_AGENT);
                    v5 = __hip_atomic_load(&pb[(pbase+5)*512], __ATOMIC_RELAXED, __HIP_MEMORY_SCOPE_AGENT);
                    v6 = __hip_atomic_load(&pb[(pbase+6)*512], __ATOMIC_RELAXED, __HIP_MEMORY_SCOPE_AGENT);
                    v7 = __hip_atomic_load(&pb[(pbase+7)*512], __ATOMIC_RELAXED, __HIP_MEMORY_SCOPE_AGENT);
                    ok = ((v0>>25)==tg) && ((v1>>25)==tg) && ((v2>>25)==tg) && ((v3>>25)==tg)
                      && ((v4>>25)==tg) && ((v5>>25)==tg) && ((v6>>25)==tg) && ((v7>>25)==tg);
                }
                if ((++spins & 255u) == 0u) {
                    if (__hip_atomic_load(abortf, __ATOMIC_RELAXED, __HIP_MEMORY_SCOPE_AGENT) != 0u ||
                        spins > (1u<<18)) {
                        __hip_atomic_store(abortf, 1u, __ATOMIC_RELAXED, __HIP_MEMORY_SCOPE_AGENT);
                        to = true; break;
                    }
                }
            }
            if (to) {
                if (tid == 0) abort_s = 1u;
            } else {
                int qs = sext25_(v0) + sext25_(v1) + sext25_(v2) + sext25_(v3)
                       + sext25_(v4) + sext25_(v5) + sext25_(v6) + sext25_(v7);
                qs += __shfl_xor(qs, 16);
                qs += __shfl_xor(qs, 32);          // lanes with same il now hold total
                if (tid < NJ) {
                    float LEd = (float)qs * INVSCALE_;
                    float rE = rE0 + kstd*nz + kg*LEd;
                    float nEv = stEv + 0.05f*(rA*aa*(stim + 500.0f*tanhf(rE*0.002f)) - 2.0f*aa*stEv - aa*aa*stE);
                    stM = nM_pre; stE = nE_pre; stI = nI_pre;
                    stMv = nMv; stEv = nEv; stIv = nIv;
                }
            }
        }
        __syncthreads();                              // B2
        if (abort_s) break;
        if (thc == NH_-1) { thc = 0; ++tbc; } else ++thc;
    }

    __syncthreads();
    if (abort_s == 0u) {
        const float* el = &eeg_l[0][0];
        for (int idx = tid; idx < NB_*NEEG; idx += NT)
            atomicAdd(&ws[OFF_EEG + idx], el[idx]);
    }
}

__global__ void k_out(const float* __restrict__ ws, const float* __restrict__ theta,
                      float* __restrict__ out)
{
    int idx = blockIdx.x*256 + threadIdx.x;
    if (idx < NB_*NEEG) out[idx] = 0.01f*theta[13]*ws[OFF_EEG + idx] - theta[14];
}

extern "C" void kernel_launch(void* const* d_in, const int* in_sizes, int n_in,
                              void* d_out, int out_size, void* d_ws, size_t ws_size,
                              hipStream_t stream)
{
    const float* input    = (const float*)d_in[0];
    const float* noise_in = (const float*)d_in[1];
    const float* hx       = (const float*)d_in[3];
    const float* hE       = (const float*)d_in[4];
    const float* sc       = (const float*)d_in[5];
    const float* dist     = (const float*)d_in[6];
    const float* w_bb     = (const float*)d_in[7];
    const float* W_in     = (const float*)d_in[8];
    const float* lm       = (const float*)d_in[10];
    const float* theta    = (const float*)d_in[11];
    float* ws  = (float*)d_ws;
    float* out = (float*)d_out;

    hipMemsetAsync(d_ws, 0, (size_t)OFF_ZEND*4, stream);                        // hdr+eeg
    hipMemsetAsync((char*)d_ws + (size_t)OFF_TBUF*4, 0xFF, (size_t)TBUF_WORDS*4, stream); // tags=127
    k_ws  <<<Nn, 256, 0, stream>>>(w_bb, sc, ws);
    k_lmt <<<(Nn + 255)/256, 256, 0, stream>>>(lm, ws);
    k_main<<<NWG, NT, 0, stream>>>(input, noise_in, hx, hE, dist, W_in, theta, ws);
    k_out <<<(NB_*NEEG + 255)/256, 256, 0, stream>>>(ws, theta, out);
}